// Round 15
// baseline (1009.306 us; speedup 1.0000x reference)
//
#include <hip/hip_runtime.h>
#include <hip/hip_bf16.h>
#include <math.h>

// Problem: input (16,1024,512) f32, codebook (8192,512) f32
#define N_ROWS 16384
#define DIM    512
#define VOCAB  8192

typedef __attribute__((ext_vector_type(4))) float f32x4;

__device__ inline void gload16(const void* g, void* l) {
    __builtin_amdgcn_global_load_lds(
        (const __attribute__((address_space(1))) void*)g,
        (__attribute__((address_space(3))) void*)l, 16, 0, 0);
}

// pack 4 floats -> 4 fp8(e4m3) bytes via HW cvt
__device__ inline int pk4_fp8(float4 v) {
    int p = __builtin_amdgcn_cvt_pk_fp8_f32(v.x, v.y, 0, false);
    return  __builtin_amdgcn_cvt_pk_fp8_f32(v.z, v.w, p, true);
}

__device__ inline void top2_ins(float s, int v, float& s1, int& i1, float& s2, int& i2) {
    if (s < s1 || (s == s1 && v < i1)) { s2 = s1; i2 = i1; s1 = s; i1 = v; }
    else if (s < s2 || (s == s2 && v < i2)) { s2 = s; i2 = v; }
}

// merge top-2 across the 16 col-lanes (validated butterfly, all lanes converge)
__device__ inline void bfly16_top2(float& s1, int& i1, float& s2, int& i2) {
#pragma unroll
    for (int off = 1; off < 16; off <<= 1) {
        float t1 = __shfl_xor(s1, off, 64); int j1 = __shfl_xor(i1, off, 64);
        float t2 = __shfl_xor(s2, off, 64); int j2 = __shfl_xor(i2, off, 64);
        bool bfirst = (t1 < s1) || (t1 == s1 && j1 < i1);
        if (bfirst) {
            float ns; int ni;
            if (s1 < t2 || (s1 == t2 && i1 < j2)) { ns = s1; ni = i1; }
            else                                   { ns = t2; ni = j2; }
            s1 = t1; i1 = j1; s2 = ns; i2 = ni;
        } else if (t1 < s2 || (t1 == s2 && j1 < i2)) { s2 = t1; i2 = j1; }
    }
}

// ---------------------------------------------------------------------------
// fp32 -> fp8 e4m3 for input x (8 elems/thread)
// ---------------------------------------------------------------------------
__global__ void k_split_x(const float* __restrict__ in, unsigned char* __restrict__ q,
                          int n8) {
    int t = blockIdx.x * 256 + threadIdx.x;
    if (t >= n8) return;
    const float4* p = reinterpret_cast<const float4*>(in) + 2 * (size_t)t;
    int2 r = make_int2(pk4_fp8(p[0]), pk4_fp8(p[1]));
    reinterpret_cast<int2*>(q)[t] = r;
}

// ---------------------------------------------------------------------------
// codebook: fp32 -> fp8 e4m3 AND exact fp32 c2[v] in one pass (validated r14)
// ---------------------------------------------------------------------------
__global__ void k_split_cb(const float* __restrict__ cb, unsigned char* __restrict__ q,
                           float* __restrict__ c2) {
    int row  = blockIdx.x * 4 + (threadIdx.x >> 6);
    int lane = threadIdx.x & 63;
    const float4* p = reinterpret_cast<const float4*>(cb + (size_t)row * DIM);
    float4 a = p[lane * 2], b = p[lane * 2 + 1];
    float s = a.x*a.x + a.y*a.y + a.z*a.z + a.w*a.w
            + b.x*b.x + b.y*b.y + b.z*b.z + b.w*b.w;
    reinterpret_cast<int2*>(q + (size_t)row * DIM)[lane] =
        make_int2(pk4_fp8(a), pk4_fp8(b));
#pragma unroll
    for (int off = 32; off > 0; off >>= 1) s += __shfl_xor(s, off, 64);
    if (lane == 0) c2[row] = s;
}

// ---------------------------------------------------------------------------
// fp8 MFMA GEMM (K = 512) + fused per-tile TOP-4 argmin (r14 GEMM body,
// recall fixed: top-2 butterfly, then knock out {i1,i2} and butterfly again
// -> exact tile top-4; failure now needs 4 simultaneous fp8-error inversions
// in one 128-col tile, P ~ 4e-10/row).
// ---------------------------------------------------------------------------
__launch_bounds__(256, 2)
__global__ void k_mfma_argmin(const unsigned char* __restrict__ xq,
                              const unsigned char* __restrict__ cbq,
                              const float* __restrict__ c2,
                              float4* __restrict__ part) {
    __shared__ __align__(16) char As[16384];   // [128 rows][128 fp8], swizzled
    __shared__ __align__(16) char Bs[16384];
    const int tid  = threadIdx.x;
    const int w    = tid >> 6;
    const int lane = tid & 63;
    const int l15  = lane & 15;
    const int lg   = lane >> 4;

    // L2-blocked XCD map (r13/r14-validated): 8192 = 8 XCD x [64 bx x 16 by]
    const int xcd = blockIdx.x & 7;
    const int i   = blockIdx.x >> 3;
    const int by  = xcd * 16 + (i & 15);
    const int bx  = i >> 4;
    const int rowBase = by * 128;
    const int colBase = bx * 128;

    f32x4 acc[2][8];
#pragma unroll
    for (int mi = 0; mi < 2; ++mi)
#pragma unroll
        for (int nj = 0; nj < 8; ++nj) acc[mi][nj] = (f32x4)0.f;

    // staging (r13/r14 scheme): chunk = 1024B = 8 rows of 128B;
    // lane -> (r = 8*chunk + lane>>3, slot = lane&7); source slot ^= row&7.
    const int r8     = lane >> 3;
    const int srcoff = ((lane & 7) ^ r8) << 4;

    for (int kt = 0; kt < 4; ++kt) {          // 4 K-tiles of 128 = K 512
        const int kb = kt << 7;
        if (kt) __syncthreads();
#pragma unroll
        for (int t = 0; t < 4; ++t) {
            int i2 = 4 * w + t;
            int r0 = 8 * i2;
            gload16(xq  + (size_t)(rowBase + r0 + r8) * 512 + kb + srcoff,
                    As + 1024 * i2);
            gload16(cbq + (size_t)(colBase + r0 + r8) * 512 + kb + srcoff,
                    Bs + 1024 * i2);
        }
        __syncthreads();
#pragma unroll
        for (int s = 0; s < 4; ++s) {         // 4 x K=32 MFMA sub-steps
            const int s16 = s * 2 + (lg >> 1);
            const int rem = (lg & 1) * 8;
            long a[2], b[8];
#pragma unroll
            for (int mi = 0; mi < 2; ++mi) {
                int r = w * 32 + mi * 16 + l15;
                a[mi] = *(const long*)(As + r * 128 + ((s16 ^ (r & 7)) << 4) + rem);
            }
#pragma unroll
            for (int nj = 0; nj < 8; ++nj) {
                int r = nj * 16 + l15;
                b[nj] = *(const long*)(Bs + r * 128 + ((s16 ^ (r & 7)) << 4) + rem);
            }
#pragma unroll
            for (int mi = 0; mi < 2; ++mi)
#pragma unroll
                for (int nj = 0; nj < 8; ++nj)
                    acc[mi][nj] = __builtin_amdgcn_mfma_f32_16x16x32_fp8_fp8(
                        a[mi], b[nj], acc[mi][nj], 0, 0, 0);
        }
    }

    // Epilogue: score = c2[v] - 2*dot; per-row TOP-4 over 128 cols.
    // C layout: col = lane&15, row = 4*(lane>>4) + reg.
    float c2v[8];
#pragma unroll
    for (int nj = 0; nj < 8; ++nj) c2v[nj] = c2[colBase + nj * 16 + l15];

#pragma unroll
    for (int mi = 0; mi < 2; ++mi) {
#pragma unroll
        for (int reg = 0; reg < 4; ++reg) {
            float sc[8]; int vv[8];
#pragma unroll
            for (int nj = 0; nj < 8; ++nj) {
                sc[nj] = fmaf(-2.f, acc[mi][nj][reg], c2v[nj]);
                vv[nj] = colBase + nj * 16 + l15;
            }
            // pass 1: top-2
            float s1 = INFINITY, s2 = INFINITY;
            int   i1 = 0x7fffffff, i2 = 0x7fffffff;
#pragma unroll
            for (int nj = 0; nj < 8; ++nj) top2_ins(sc[nj], vv[nj], s1, i1, s2, i2);
            bfly16_top2(s1, i1, s2, i2);
            // pass 2: knock out {i1,i2}, top-2 again -> ranks 3,4
            float s3 = INFINITY, s4 = INFINITY;
            int   i3 = 0x7fffffff, i4 = 0x7fffffff;
#pragma unroll
            for (int nj = 0; nj < 8; ++nj) {
                bool ex = (vv[nj] == i1) || (vv[nj] == i2);
                float sx = ex ? INFINITY   : sc[nj];
                int   vx = ex ? 0x7fffffff : vv[nj];
                top2_ins(sx, vx, s3, i3, s4, i4);
            }
            bfly16_top2(s3, i3, s4, i4);
            if (l15 == 0) {
                int row = rowBase + w * 32 + mi * 16 + 4 * lg + reg;
                part[(size_t)row * 128 + bx * 2] =
                    make_float4(s1, __int_as_float(i1), s2, __int_as_float(i2));
                part[(size_t)row * 128 + bx * 2 + 1] =
                    make_float4(s3, __int_as_float(i3), s4, __int_as_float(i4));
            }
        }
    }
}

// ---------------------------------------------------------------------------
// Per-row final: approx global min over 64 tile-top4s; exact fp32 rescore of
// all candidates within min+16.0 (~9 sigma of fp8 approx-error spread);
// lexicographic (score, idx) min == reference argmin semantics.
// ---------------------------------------------------------------------------
__global__ void k_select(const float4* __restrict__ part,
                         const float* __restrict__ x,
                         const float* __restrict__ cb,
                         const float* __restrict__ c2,
                         float* __restrict__ out_idx_f,
                         int* __restrict__ idx_i,
                         int* __restrict__ used) {
    int wv   = threadIdx.x >> 6;
    int lane = threadIdx.x & 63;
    int row  = blockIdx.x * 4 + wv;
    float4 pa = part[(size_t)row * 128 + 2 * lane];
    float4 pb = part[(size_t)row * 128 + 2 * lane + 1];
    float ss[4] = {pa.x, pa.z, pb.x, pb.z};
    int   ii[4] = {__float_as_int(pa.y), __float_as_int(pa.w),
                   __float_as_int(pb.y), __float_as_int(pb.w)};
    float gm = ss[0];
#pragma unroll
    for (int off = 1; off < 64; off <<= 1) gm = fminf(gm, __shfl_xor(gm, off, 64));
    float thresh = gm + 16.0f;
    unsigned long long m[4];
#pragma unroll
    for (int q = 0; q < 4; ++q) m[q] = __ballot(ss[q] <= thresh);
    float be = INFINITY; int bi = 0x7fffffff;
    const float4* xr = reinterpret_cast<const float4*>(x + (size_t)row * DIM);
#pragma unroll
    for (int q = 0; q < 4; ++q) {
        while (m[q]) {
            int t = __ffsll(m[q]) - 1; m[q] &= m[q] - 1;
            int vi = __shfl(ii[q], t);
            const float4* cr = reinterpret_cast<const float4*>(cb + (size_t)vi * DIM);
            float d = 0.f;
#pragma unroll
            for (int p = 0; p < 2; ++p) {
                float4 a = xr[p * 64 + lane];
                float4 b = cr[p * 64 + lane];
                d += a.x * b.x + a.y * b.y + a.z * b.z + a.w * b.w;
            }
#pragma unroll
            for (int off = 1; off < 64; off <<= 1) d += __shfl_xor(d, off, 64);
            float se = c2[vi] - 2.f * d;
            if (se < be || (se == be && vi < bi)) { be = se; bi = vi; }
        }
    }
    if (lane == 0) {
        out_idx_f[row] = (float)bi;
        idx_i[row]     = bi;
        used[bi]       = 1;
    }
}

__global__ void k_streak(const int* __restrict__ streak_in,
                         const int* __restrict__ used,
                         float* __restrict__ out) {
    int v = blockIdx.x * 256 + threadIdx.x;
    if (v < VOCAB) out[v] = used[v] ? 0.f : (float)(streak_in[v] + 1);
}

__global__ void k_gather(const float* __restrict__ cb,
                         const int* __restrict__ idx_i,
                         float* __restrict__ out) {
    size_t t  = (size_t)blockIdx.x * 256 + threadIdx.x;
    int    n  = (int)(t >> 7);
    int    d4 = (int)(t & 127);
    reinterpret_cast<float4*>(out)[t] =
        reinterpret_cast<const float4*>(cb + (size_t)idx_i[n] * DIM)[d4];
}

extern "C" void kernel_launch(void* const* d_in, const int* in_sizes, int n_in,
                              void* d_out, int out_size, void* d_ws, size_t ws_size,
                              hipStream_t stream) {
    const float* x      = (const float*)d_in[0];
    const float* cb     = (const float*)d_in[1];
    const int*   streak = (const int*)d_in[2];

    float* out       = (float*)d_out;
    float* out_embed = out;
    float* out_idx   = out + (size_t)N_ROWS * DIM;
    float* out_strk  = out_idx + N_ROWS;

    char* ws = (char*)d_ws;
    unsigned char* xq  = (unsigned char*)(ws);                  // 8.4 MB
    unsigned char* cbq = (unsigned char*)(ws + (9u << 20));     // 4.2 MB
    float* c2    = (float*)(ws + (14u << 20));                  // 32 KB
    int*   idx_i = (int*)(ws + (14u << 20) + (1u << 16));       // 64 KB
    int*   used  = (int*)(ws + (14u << 20) + (2u << 16));       // 32 KB
    float4* part = (float4*)(ws + (16u << 20));                 // 32 MB

    hipMemsetAsync(used, 0, VOCAB * sizeof(int), stream);
    k_split_x<<<(N_ROWS * DIM / 8) / 256, 256, 0, stream>>>(x, xq, N_ROWS * DIM / 8);
    k_split_cb<<<VOCAB / 4, 256, 0, stream>>>(cb, cbq, c2);
    k_mfma_argmin<<<8192, 256, 0, stream>>>(xq, cbq, c2, part);
    k_select<<<N_ROWS / 4, 256, 0, stream>>>(part, x, cb, c2, out_idx, idx_i, used);
    k_streak<<<VOCAB / 256, 256, 0, stream>>>(streak, used, out_strk);
    k_gather<<<(N_ROWS * DIM / 4) / 256, 256, 0, stream>>>(cb, idx_i, out_embed);
}